// Round 7
// baseline (47.363 us; speedup 1.0000x reference)
//
#include <hip/hip_runtime.h>
#include <hip/hip_bf16.h>

typedef float f32x4 __attribute__((ext_vector_type(4)));
typedef long  l2    __attribute__((ext_vector_type(2)));

// ---------------------------------------------------------------------------
// async global->LDS, 16B per lane. LDS dest is wave-uniform base (+lane*16).
// ---------------------------------------------------------------------------
__device__ __forceinline__ void gld16(const void* g, void* l) {
    __builtin_amdgcn_global_load_lds(
        (const __attribute__((address_space(1))) void*)g,
        (__attribute__((address_space(3))) void*)l,
        16, 0, 0);
}

// gelu, tanh approximation (matches jax.nn.gelu approximate=True)
__device__ __forceinline__ float gelu_tanh(float x) {
    float u = 0.7978845608028654f * x * (1.0f + 0.044715f * x * x);
    float e = __expf(2.0f * u);
    float t = 1.0f - 2.0f / (e + 1.0f);   // tanh(u)
    return 0.5f * x * (1.0f + t);
}

// ---------------------------------------------------------------------------
// Pre-permuted fp8 storage layout (both A[M][K] and BT[N][K]):
// within each row's 64B k-segment:
//   step 1 (pair ks-halves): chunk g (16B) = orig k-bytes [g*8,+8) ++ [32+g*8,+8)
//   step 2 (bank swizzle):   stored at chunk position c = g ^ ((row>>1)&3)
// GEMM reads one ds_read_b128 per fragment-pair (lo 8B = ks0, hi = ks1),
// conflict-free across the wave. (Verified round 3: SQ_LDS_BANK_CONFLICT = 0.)
// ---------------------------------------------------------------------------

// Fused quantize kernel: blocks [0, nA) do x -> Aq; blocks [nA, nA+nB) do
// w -> BTq (transpose via LDS). Single launch so the two halves overlap.
__global__ __launch_bounds__(256) void quant_fused_kernel(
        const float* __restrict__ x,  unsigned char* __restrict__ Aq,
        const float* __restrict__ w,  unsigned char* __restrict__ BTq,
        int nA, int K, int N) {
    __shared__ unsigned char lds[64 * 68];
    const int tid = threadIdx.x;

    if (blockIdx.x < nA) {
        // ---- quantA: 256 threads x float4
        int i = blockIdx.x * 256 + tid;
        float4 v = reinterpret_cast<const float4*>(x)[i];
        int pk = 0;
        pk = __builtin_amdgcn_cvt_pk_fp8_f32(v.x, v.y, pk, false);
        pk = __builtin_amdgcn_cvt_pk_fp8_f32(v.z, v.w, pk, true);
        const long k4 = (long)i * 4;
        const int  row = (int)(k4 / K);
        const int  k   = (int)(k4 % K);
        const int  o   = k & 63;
        const int  g   = (o & 31) >> 3;
        const int  s   = (o & 7) + ((o >> 5) & 1) * 8;
        const int  c   = g ^ ((row >> 1) & 3);
        *reinterpret_cast<unsigned int*>(
            Aq + (long)row * K + (k & ~63) + (c << 4) + s) = (unsigned int)pk;
        return;
    }

    // ---- quantBT: 64x64 tile transpose through LDS
    const int bid = blockIdx.x - nA;
    const int n0 = (bid & (N / 64 - 1)) * 64;
    const int k0 = (bid / (N / 64)) * 64;

    #pragma unroll
    for (int p = 0; p < 4; ++p) {
        int s = p * 256 + tid;
        int r = s >> 4;          // k within tile (0..63)
        int c = s & 15;          // float4 group (covers n = 4c..4c+3)
        float4 v = *reinterpret_cast<const float4*>(
            w + (long)(k0 + r) * N + n0 + c * 4);
        int pk = 0;
        pk = __builtin_amdgcn_cvt_pk_fp8_f32(v.x, v.y, pk, false);
        pk = __builtin_amdgcn_cvt_pk_fp8_f32(v.z, v.w, pk, true);
        *reinterpret_cast<unsigned int*>(&lds[r * 68 + c * 4]) = (unsigned int)pk;
    }
    __syncthreads();
    #pragma unroll
    for (int p = 0; p < 4; ++p) {
        int sidx = p * 256 + tid;
        int n  = sidx >> 4;      // n within tile (0..63)
        int kg = sidx & 15;      // k group of 4 (orig offset kg*4)
        unsigned int wv = 0;
        #pragma unroll
        for (int j = 0; j < 4; ++j)
            wv |= (unsigned int)lds[(kg * 4 + j) * 68 + n] << (8 * j);
        const int nn = n0 + n;
        const int o  = kg * 4;
        const int g  = (o & 31) >> 3;
        const int s  = (o & 7) + ((o >> 5) & 1) * 8;
        const int c  = g ^ ((nn >> 1) & 3);
        *reinterpret_cast<unsigned int*>(
            BTq + (long)nn * K + k0 + (c << 4) + s) = wv;
    }
}

// ---------------------------------------------------------------------------
// fp8 GEMM, 128x256 tile, BK=64, 8 waves (2M x 4N).
// 2 LDS buffers (48 KB total) -> 2-3 blocks/CU for inter-block overlap.
// Per K-tile: 2 phases of 16 MFMA; 3 half-tile stages (A, B0 | B1) for tile
// t+1 into the other buffer; boundary vmcnt(0) drain (stages issued a full
// tile earlier, operands ~94% L2-resident, so drain is cheap).
// Epilogue: wave-private LDS transpose -> nontemporal float4 stores.
// ---------------------------------------------------------------------------
__global__ __launch_bounds__(512, 4) void gemm_fp8_kernel(
        const unsigned char* __restrict__ A,   // [M][K] fp8 (permuted layout)
        const unsigned char* __restrict__ BT,  // [N][K] fp8 (permuted layout)
        const float* __restrict__ bias,        // [N]
        float* __restrict__ out,               // [M][N] f32
        int M, int N, int K) {
    constexpr int BM = 128, BN = 256, BK = 64;
    __shared__ unsigned char lds[2][(BM + BN) * BK];   // 2 x 24 KB = 48 KB

    const int tid  = threadIdx.x;
    const int lane = tid & 63;
    const int wid  = tid >> 6;            // 0..7
    const int wm   = wid >> 2;            // 0..1 (64 rows each)
    const int wn   = wid & 3;             // 0..3 (64 cols each)

    // XCD mapping: 8 XCDs over the 32x16 tile grid, each an 8x8 rectangle
    // (~3 MB working set per XCD L2). Bijective: 512 = 8 * 64.
    const int bid = blockIdx.x;
    const int xcd = bid & 7, idx = bid >> 3;            // idx 0..63
    const int tile_m = (xcd >> 1) * 8 + (idx & 7);      // 0..31
    const int tile_n = (xcd & 1) * 8 + (idx >> 3);      // 0..15
    const int m0 = tile_m * BM, n0 = tile_n * BN;

    const int lrow = lane & 15;           // fragment row within 16
    const int kgrp = lane >> 4;           // 0..3, k-group
    const int chunkoff = ((kgrp ^ ((lrow >> 1) & 3)) << 4);

    // staging: one gld16 per thread per 8KB half (128 rows x 64B)
    const int srow   = tid >> 2;          // 0..127
    const int schunk = (tid & 3) << 4;
    const unsigned char* gA = A  + (long)(m0 + srow) * K + schunk;
    const unsigned char* gB = BT + (long)(n0 + srow) * K + schunk;

    const int aBase = (wm * 64 + lrow) * 64 + chunkoff;            // A rows [0,128)
    const int bBase = 8192 + (wn * 64 + lrow) * 64 + chunkoff;     // B rows [0,256)

    f32x4 acc[4][4] = {};

    const int NT = K / BK;  // 16

#define STAGE_A(BB, TT)                                                   \
    gld16(gA + (long)(TT) * BK, &lds[BB][wid * 1024])
#define STAGE_B(BB, H, TT)                                                \
    gld16(gB + (long)(H) * 128 * K + (long)(TT) * BK,                     \
          &lds[BB][8192 + (H) * 8192 + wid * 1024])

#define MFMA_Q(AI0, BJ0, AR, BR)                                          \
    _Pragma("unroll") for (int ks = 0; ks < 2; ++ks)                      \
    _Pragma("unroll") for (int fi = 0; fi < 2; ++fi)                      \
    _Pragma("unroll") for (int fj = 0; fj < 2; ++fj)                      \
        acc[(AI0) + fi][(BJ0) + fj] =                                     \
            __builtin_amdgcn_mfma_f32_16x16x32_fp8_fp8(                   \
                AR[fi][ks], BR[fj][ks], acc[(AI0) + fi][(BJ0) + fj], 0, 0, 0)

    // prologue: stage tile 0 into buf 0
    STAGE_A(0, 0); STAGE_B(0, 0, 0); STAGE_B(0, 1, 0);
    asm volatile("s_waitcnt vmcnt(0)" ::: "memory");
    __builtin_amdgcn_s_barrier();

    for (int t = 0; t < NT; ++t) {
        const int cur = t & 1, nxt = cur ^ 1;
        const unsigned char* sL = &lds[cur][0];
        const bool st = (t + 1 < NT);
        l2 a01[2], a23[2], b01[2], b23[2];

        // ---- phase 0: stages A,B0 of t+1; reads a01,b01,b23; MFMA rows 0-1
        if (st) { STAGE_A(nxt, t + 1); STAGE_B(nxt, 0, t + 1); }
        #pragma unroll
        for (int f = 0; f < 2; ++f) {
            a01[f] = *reinterpret_cast<const l2*>(sL + aBase + f * 1024);
            b01[f] = *reinterpret_cast<const l2*>(sL + bBase + f * 1024);
            b23[f] = *reinterpret_cast<const l2*>(sL + bBase + 2048 + f * 1024);
        }
        __builtin_amdgcn_s_barrier();
        asm volatile("s_waitcnt lgkmcnt(0)" ::: "memory");
        __builtin_amdgcn_sched_barrier(0);
        __builtin_amdgcn_s_setprio(1);
        MFMA_Q(0, 0, a01, b01);
        MFMA_Q(0, 2, a01, b23);
        __builtin_amdgcn_s_setprio(0);

        // ---- phase 1: stage B1 of t+1; reads a23; MFMA rows 2-3
        if (st) { STAGE_B(nxt, 1, t + 1); }
        #pragma unroll
        for (int f = 0; f < 2; ++f)
            a23[f] = *reinterpret_cast<const l2*>(sL + aBase + 2048 + f * 1024);
        __builtin_amdgcn_s_barrier();
        asm volatile("s_waitcnt lgkmcnt(0)" ::: "memory");
        __builtin_amdgcn_sched_barrier(0);
        __builtin_amdgcn_s_setprio(1);
        MFMA_Q(2, 0, a23, b01);
        MFMA_Q(2, 2, a23, b23);
        __builtin_amdgcn_s_setprio(0);
        __builtin_amdgcn_sched_barrier(0);

        // ---- tile boundary: drain this wave's stages for t+1, sync
        if (t < NT - 1) {
            asm volatile("s_waitcnt vmcnt(0)" ::: "memory");
            __builtin_amdgcn_sched_barrier(0);
            __builtin_amdgcn_s_barrier();
        }
    }

    // ------------------------------------------------------------------
    // epilogue: bias + gelu, wave-private LDS transpose, nt float4 stores.
    // C/D frag layout: col = lrow, row = kgrp*4 + r.
    // ------------------------------------------------------------------
    __syncthreads();   // all LDS traffic of the loop complete; safe to reuse
    float* eplds = reinterpret_cast<float*>(&lds[0][0]) + wid * 1088; // 16x68
    const int  col0   = n0 + wn * 64;
    const long rbase0 = m0 + wm * 64;
    float bv[4];
    #pragma unroll
    for (int bj = 0; bj < 4; ++bj) bv[bj] = bias[col0 + bj * 16 + lrow];

    #pragma unroll
    for (int ai = 0; ai < 4; ++ai) {
        #pragma unroll
        for (int bj = 0; bj < 4; ++bj) {
            #pragma unroll
            for (int r = 0; r < 4; ++r) {
                float xv = acc[ai][bj][r] + bv[bj];
                eplds[(kgrp * 4 + r) * 68 + bj * 16 + lrow] = gelu_tanh(xv);
            }
        }
        #pragma unroll
        for (int s = 0; s < 4; ++s) {
            f32x4 v = *reinterpret_cast<const f32x4*>(
                eplds + (s * 4 + kgrp) * 68 + lrow * 4);
            __builtin_nontemporal_store(v, reinterpret_cast<f32x4*>(
                out + (rbase0 + ai * 16 + s * 4 + kgrp) * N + col0 + lrow * 4));
        }
    }
#undef STAGE_A
#undef STAGE_B
#undef MFMA_Q
}

// ---------------------------------------------------------------------------
extern "C" void kernel_launch(void* const* d_in, const int* in_sizes, int n_in,
                              void* d_out, int out_size, void* d_ws, size_t ws_size,
                              hipStream_t stream) {
    const float* x    = (const float*)d_in[0];   // [tokens][d_in]
    const float* w    = (const float*)d_in[1];   // [d_in][units]
    const float* bias = (const float*)d_in[2];   // [units]
    float* out = (float*)d_out;

    const int units  = in_sizes[2];              // 4096
    const int dmodel = in_sizes[1] / units;      // 1024
    const int tokens = in_sizes[0] / dmodel;     // 4096

    unsigned char* Aq  = (unsigned char*)d_ws;                 // [tokens][dmodel] fp8
    unsigned char* BTq = Aq + (size_t)tokens * dmodel;         // [units][dmodel] fp8

    const int nA = tokens * dmodel / 4 / 256;                  // 4096 blocks
    const int nB = (units / 64) * (dmodel / 64);               // 1024 blocks
    quant_fused_kernel<<<dim3(nA + nB), dim3(256), 0, stream>>>(
        x, Aq, w, BTq, nA, dmodel, units);

    const int nblocks = (tokens / 128) * (units / 256);
    gemm_fp8_kernel<<<dim3(nblocks), dim3(512), 0, stream>>>(
        Aq, BTq, bias, out, tokens, units, dmodel);
}